// Round 8
// baseline (1030.482 us; speedup 1.0000x reference)
//
#include <hip/hip_runtime.h>

#define N_NODES 20000
#define N_PAD   20096      /* 157*128 */
#define N_EDGES 320000
#define F_IN 4644
#define KP0  4672          /* F_IN padded to 32 */
#define NP2  4736          /* F_IN padded to 128 */
#define F_H 512
#define EPSV 1e-5f
#define SZL 10240000L      /* N_NODES*F_H floats */
#define ACT 5200000L       /* floats per bf16 activation buffer: >= N_PAD*F_H/2 = 5,144,576 */

using short8 = __attribute__((ext_vector_type(8))) short;
using f32x4  = __attribute__((ext_vector_type(4))) float;

__device__ inline unsigned short f2b(float f){
  union{float f; unsigned u;} v; v.f=f;
  unsigned u = v.u + 0x7fffu + ((v.u>>16)&1u);
  return (unsigned short)(u>>16);
}
__device__ inline float blo(unsigned v){ return __uint_as_float(v<<16); }
__device__ inline float bhi(unsigned v){ return __uint_as_float(v & 0xffff0000u); }

#define GLDS(g, l) __builtin_amdgcn_global_load_lds( \
    (const __attribute__((address_space(1))) void*)(g), \
    (__attribute__((address_space(3))) void*)(l), 16, 0, 0)

// ---------------- utility / CSR ----------------
__global__ void k_zero_i(int* p, int n){ int i = blockIdx.x*blockDim.x+threadIdx.x; if(i<n) p[i]=0; }
__global__ void k_zero_f(float* p, int n){ int i = blockIdx.x*blockDim.x+threadIdx.x; if(i<n) p[i]=0.f; }

__global__ void k_degree(const int* __restrict__ dst, int* __restrict__ deg){
  int e = blockIdx.x*blockDim.x+threadIdx.x;
  if (e < N_EDGES) atomicAdd(&deg[dst[e]], 1);
}
__global__ void k_dinv(const int* __restrict__ deg, float* __restrict__ dinv){
  int i = blockIdx.x*blockDim.x+threadIdx.x;
  if (i < N_NODES) dinv[i] = rsqrtf((float)(deg[i]+1));
}
__global__ __launch_bounds__(1024) void k_scan(const int* __restrict__ deg, int* __restrict__ rowptr){
  __shared__ int sh[1024];
  int t = threadIdx.x;
  const int C = 20;
  int base = t*C;
  int loc[C];
  int s = 0;
  #pragma unroll
  for (int i=0;i<C;i++){ int idx=base+i; int v = (idx<N_NODES)?deg[idx]:0; loc[i]=s; s+=v; }
  sh[t]=s; __syncthreads();
  for (int off=1; off<1024; off<<=1){
    int v = (t>=off)?sh[t-off]:0;
    __syncthreads();
    sh[t]+=v;
    __syncthreads();
  }
  int excl = (t==0)?0:sh[t-1];
  #pragma unroll
  for (int i=0;i<C;i++){ int idx=base+i; if(idx<N_NODES) rowptr[idx]=excl+loc[i]; }
  if (t==1023) rowptr[N_NODES]=sh[1023];
}
__global__ void k_copy_i(const int* __restrict__ a, int* __restrict__ b, int n){
  int i = blockIdx.x*blockDim.x+threadIdx.x; if(i<n) b[i]=a[i];
}
__global__ void k_scatter(const int* __restrict__ src, const int* __restrict__ dst,
                          int* __restrict__ cursor, int* __restrict__ colsrc){
  int e = blockIdx.x*blockDim.x+threadIdx.x;
  if (e < N_EDGES){
    int p = atomicAdd(&cursor[dst[e]], 1);
    colsrc[p] = src[e];
  }
}

// ---------------- conversions ----------------
__global__ void k_cvtT(const float* __restrict__ B, unsigned short* __restrict__ BT,
                       int K, int N, int NP, int KP){
  int t = blockIdx.x*blockDim.x+threadIdx.x;
  if (t >= NP*KP) return;
  int n = t / KP, k = t % KP;
  float v = (n < N && k < K) ? B[(long)k*N + n] : 0.f;
  BT[t] = f2b(v);
}
__global__ void k_red(const float* __restrict__ p0, const float* __restrict__ p1,
                      unsigned short* __restrict__ tb){
  long i = ((long)blockIdx.x*256 + threadIdx.x)*4;
  if (i >= SZL) return;
  float4 a = *(const float4*)&p0[i];
  float4 b = *(const float4*)&p1[i];
  unsigned short o[4] = { f2b(a.x+b.x), f2b(a.y+b.y), f2b(a.z+b.z), f2b(a.w+b.w) };
  *(uint2*)&tb[i] = *(uint2*)o;
}

// ---------------- bf16 MFMA GEMM: dbuf + swizzles + full-line epilogue ----------------
// C[M,N] = A[M,K]@BT[N,K]^T. BT bf16 row-major fully padded.
// AF32=0: A bf16 row-major with >= tile rows readable, staged via global_load_lds.
// AF32=1: A fp32 [M][lda] raw (row/K-tail guarded), reg-staged with fused f2b convert
//         (load next tile early -> MFMA -> cvt+ds_write to back buffer). T14 pattern.
// 128x128 tile, BK=32, 4 waves (2x2), 4x4 16x16x32 frags/wave. gridDim.z = split-K slices.
// XCD-aware bijective block swizzle (T1/m204). LDS k-slot swizzle on 16B slots:
// stored slot = q ^ ((row>>1)&3); GLDS path swizzles the global SOURCE (dest linear),
// reg-staged path swizzles the ds_write DEST; ds_read uses the same XOR (involution).
// Epilogue: per-wave LDS transpose -> float4 / 4xushort stores (full cache lines).
template<int AF32, int OUTB, int RELU>
__global__ __launch_bounds__(256) void k_gb(
    const void* __restrict__ Av, const unsigned short* __restrict__ BT,
    const float* __restrict__ bias, void* __restrict__ Cvoid,
    int M, int N, int KP, int lda, int ldc, int kchunk, long zstride)
{
  // [0..1] = A double-buffer, [2..3] = B double-buffer; epilogue reuses as fp32 scratch
  __shared__ unsigned short smem[4][4096];
  const int tid  = threadIdx.x;
  // ---- XCD-aware bijective swizzle over flattened (x,y) ----
  const int gx   = gridDim.x;
  const int nwg  = gx * gridDim.y;
  const int orig = blockIdx.x + gx * blockIdx.y;
  const int q = nwg >> 3, r = nwg & 7;
  const int xcd = orig & 7, sub = orig >> 3;
  const int wg  = (xcd < r ? xcd*(q+1) : r*(q+1) + (xcd - r)*q) + sub;
  const int bn  = (wg % gx) * 128;
  const int bm  = (wg / gx) * 128;
  const int z    = blockIdx.z;
  const int wave = tid >> 6, lane = tid & 63;
  const int wm = (wave & 1) * 64, wn = (wave >> 1) * 64;
  const int l15 = lane & 15, l4 = lane >> 4;
  const int k0beg = z * kchunk;
  const int kend0 = k0beg + kchunk;
  const int k0end = (kend0 < KP) ? kend0 : KP;

  f32x4 acc[4][4];
  #pragma unroll
  for (int m=0;m<4;m++)
    #pragma unroll
    for (int n=0;n<4;n++) acc[m][n] = (f32x4){0.f,0.f,0.f,0.f};

  // 16B chunks: tile = 512 chunks = 128 rows x 4 slots; chunk c -> row c>>2, slot c&3.
  const int c0 = wave*64 + lane;
  const int c1 = c0 + 256;
  const long ar0 = bm + (c0 >> 2); const int as0 = ((c0 & 3) ^ ((c0 >> 3) & 3))*8;
  const long ar1 = bm + (c1 >> 2); const int as1 = ((c1 & 3) ^ ((c1 >> 3) & 3))*8;
  const long br0 = bn + (c0 >> 2);
  const long br1 = bn + (c1 >> 2);
  const int ldA0 = wave*512;          // ushort offset of this wave's chunk group (issue 0)
  const int ldA1 = 2048 + wave*512;   // issue 1

  // reg-staged A (AF32): natural slot q0, swizzled ds_write dest
  const int lr0 = c0 >> 2, q0 = c0 & 3;     // c1&3 == q0 (256%4==0)
  const int lr1 = lr0 + 64;
  const int adst0 = lr0*32 + (q0 ^ ((lr0 >> 1) & 3))*8;
  const int adst1 = lr1*32 + (q0 ^ ((lr1 >> 1) & 3))*8;
  const float* Af = (const float*)Av;
  const unsigned short* Ab = (const unsigned short*)Av;
  const bool aok0 = ar0 < M, aok1 = ar1 < M;

  // read-side swizzle: k-slot l4 of row (…+l15) lives at slot l4 ^ ((l15>>1)&3)
  const int kro = (l4 ^ ((l15 >> 1) & 3)) * 8;

  const int nit = (k0end - k0beg) >> 5;

  // fp32 A chunk loader: 8 cols starting at c (guarded)
  auto ldA8 = [&](const float* p, bool rowok, int c, float4& v0, float4& v1){
    v0 = (float4){0.f,0.f,0.f,0.f}; v1 = v0;
    if (rowok) {
      if (c + 7 < lda) { v0 = *(const float4*)(p + c); v1 = *(const float4*)(p + c + 4); }
      else {
        float t[8];
        #pragma unroll
        for (int j=0;j<8;j++) t[j] = (c + j < lda) ? p[c + j] : 0.f;
        v0 = (float4){t[0],t[1],t[2],t[3]}; v1 = (float4){t[4],t[5],t[6],t[7]};
      }
    }
  };
  auto wrA = [&](unsigned short* dst, float4 v0, float4 v1){
    unsigned short o[8] = { f2b(v0.x),f2b(v0.y),f2b(v0.z),f2b(v0.w),
                            f2b(v1.x),f2b(v1.y),f2b(v1.z),f2b(v1.w) };
    *(short8*)dst = *(short8*)o;
  };

  // prologue: stage tile 0 into buffer 0
  if (AF32) {
    float4 p00,p01,p10,p11;
    ldA8(Af + ar0*lda, aok0, k0beg + q0*8, p00, p01);
    ldA8(Af + ar1*lda, aok1, k0beg + q0*8, p10, p11);
    wrA(&smem[0][adst0], p00, p01);
    wrA(&smem[0][adst1], p10, p11);
    GLDS(BT + br0*KP + (k0beg + as0), &smem[2][ldA0]);
    GLDS(BT + br1*KP + (k0beg + as1), &smem[2][ldA1]);
  } else {
    GLDS(Ab + ar0*lda + (k0beg + as0), &smem[0][ldA0]);
    GLDS(Ab + ar1*lda + (k0beg + as1), &smem[0][ldA1]);
    GLDS(BT + br0*KP + (k0beg + as0), &smem[2][ldA0]);
    GLDS(BT + br1*KP + (k0beg + as1), &smem[2][ldA1]);
  }
  __syncthreads();

  int cur = 0;
  for (int it = 0; it < nit; ++it) {
    float4 p00,p01,p10,p11;
    const bool pf = (it + 1 < nit);
    if (pf) {
      const int kn = k0beg + (it+1)*32;
      if (AF32) {
        ldA8(Af + ar0*lda, aok0, kn + q0*8, p00, p01);
        ldA8(Af + ar1*lda, aok1, kn + q0*8, p10, p11);
      } else {
        GLDS(Ab + ar0*lda + (kn + as0), &smem[cur^1][ldA0]);
        GLDS(Ab + ar1*lda + (kn + as1), &smem[cur^1][ldA1]);
      }
      GLDS(BT + br0*KP + (kn + as0), &smem[2+(cur^1)][ldA0]);
      GLDS(BT + br1*KP + (kn + as1), &smem[2+(cur^1)][ldA1]);
    }

    short8 af[4], bf[4];
    #pragma unroll
    for (int m=0;m<4;m++) af[m] = *(const short8*)&smem[cur][(wm + m*16 + l15)*32 + kro];
    #pragma unroll
    for (int n=0;n<4;n++) bf[n] = *(const short8*)&smem[2+cur][(wn + n*16 + l15)*32 + kro];
    #pragma unroll
    for (int m=0;m<4;m++)
      #pragma unroll
      for (int n=0;n<4;n++)
        acc[m][n] = __builtin_amdgcn_mfma_f32_16x16x32_bf16(af[m], bf[n], acc[m][n], 0, 0, 0);

    if (AF32 && pf) {
      wrA(&smem[cur^1][adst0], p00, p01);   // back buffer: nobody reads it this iter
      wrA(&smem[cur^1][adst1], p10, p11);
    }
    __syncthreads();   // drains prefetch + all waves' ds ops
    cur ^= 1;
  }

  // ---- full-line epilogue via per-wave LDS transpose ----
  // per wave: 16 rows x 64 cols fp32, row stride 68 (16B-aligned, conflict-light)
  float* eb = ((float*)smem) + wave*1088;   // 4*1088*4B = 17408B <= 32KB
  float* Cf = ((float*)Cvoid) + z*zstride;
  unsigned short* Cb = (unsigned short*)Cvoid;
  #pragma unroll
  for (int m=0;m<4;m++){
    #pragma unroll
    for (int n=0;n<4;n++)
      #pragma unroll
      for (int r2=0;r2<4;r2++)
        eb[(l4*4+r2)*68 + n*16 + l15] = acc[m][n][r2];
    __syncthreads();
    const int row0 = bm + wm + m*16;
    #pragma unroll
    for (int i=0;i<4;i++){
      int idx = i*64 + lane;          // 0..255 float4-chunks of the 16x64 tile
      int rr  = idx >> 4;             // 0..15
      int c4  = (idx & 15) * 4;       // 0,4,..,60
      int row = row0 + rr;
      int col = bn + wn + c4;
      if (row < M) {
        float4 v = *(float4*)&eb[rr*68 + c4];
        float vv[4] = {v.x, v.y, v.z, v.w};
        if (col + 3 < N) {
          #pragma unroll
          for (int j=0;j<4;j++){
            float zz = vv[j] + (bias ? bias[col+j] : 0.f);
            vv[j] = RELU ? fmaxf(zz, 0.f) : zz;
          }
          if (OUTB) {
            unsigned short o[4] = { f2b(vv[0]), f2b(vv[1]), f2b(vv[2]), f2b(vv[3]) };
            *(uint2*)&Cb[(long)row*ldc + col] = *(uint2*)o;
          } else {
            float4 ov = {vv[0], vv[1], vv[2], vv[3]};
            *(float4*)&Cf[(long)row*ldc + col] = ov;
          }
        } else {
          #pragma unroll
          for (int j=0;j<4;j++){
            int cc = col + j;
            if (cc < N) {
              float zz = vv[j] + (bias ? bias[cc] : 0.f);
              if (RELU) zz = fmaxf(zz, 0.f);
              if (OUTB) Cb[(long)row*ldc + cc] = f2b(zz);
              else      Cf[(long)row*ldc + cc] = zz;
            }
          }
        }
      }
    }
    __syncthreads();
  }
}

// ---------------- GCN aggregation (bf16 h, fp32 accumulate) ----------------
__global__ __launch_bounds__(256) void k_agg(const unsigned short* __restrict__ h,
    const int* __restrict__ rowptr, const int* __restrict__ colsrc,
    const float* __restrict__ dinv, const float* __restrict__ bias,
    float* __restrict__ out)
{
  int d = blockIdx.x;
  int t = threadIdx.x;                 // channel pair 2t,2t+1
  const unsigned* h32 = (const unsigned*)h;
  float di = dinv[d];
  int beg = rowptr[d], end = rowptr[d+1];
  float a0 = 0.f, a1 = 0.f;
  for (int e = beg; e < end; e++) {
    int s = colsrc[e];
    float cf = dinv[s]*di;
    unsigned v = h32[(long)s*256 + t];
    a0 += blo(v)*cf;
    a1 += bhi(v)*cf;
  }
  unsigned v = h32[(long)d*256 + t];
  float sc = di*di;
  a0 += blo(v)*sc;
  a1 += bhi(v)*sc;
  float2 o; o.x = a0 + bias[2*t]; o.y = a1 + bias[2*t+1];
  *(float2*)&out[(long)d*F_H + 2*t] = o;
}

// ---------------- GraphNorm: fused sum+sumsq, then normalize ----------------
#define STAT_ROWS 50
__global__ __launch_bounds__(512) void k_stats(const float* __restrict__ x,
    float* __restrict__ msum, float* __restrict__ ssum){
  int c = threadIdx.x;
  int r0 = blockIdx.x*STAT_ROWS;
  float s = 0.f, s2 = 0.f;
  for (int r=r0;r<r0+STAT_ROWS;r++){ float v = x[(long)r*F_H+c]; s += v; s2 += v*v; }
  atomicAdd(&msum[c], s);
  atomicAdd(&ssum[c], s2);
}
// mode 0: l0f=y, l0b=bf16(y), jkb=bf16(y); mode 1: loutb=bf16(y+l0f), jkb=max; mode 2: jkb=max
__global__ __launch_bounds__(512) void k_final(const float* __restrict__ x,
    const float* __restrict__ msum, const float* __restrict__ ssum,
    const float* __restrict__ w, const float* __restrict__ b, const float* __restrict__ a,
    float* __restrict__ l0f, unsigned short* __restrict__ loutb,
    unsigned short* __restrict__ jkb, int mode)
{
  int c = threadIdx.x;
  float mean = msum[c]*(1.f/N_NODES);
  float aa = a[c];
  float var = ssum[c]*(1.f/N_NODES) - mean*mean*aa*(2.f-aa);
  float inv = rsqrtf(var + EPSV);
  float am = aa*mean;
  float wc = w[c], bc = b[c];
  int r0 = blockIdx.x*STAT_ROWS;
  for (int r=r0;r<r0+STAT_ROWS;r++){
    long idx = (long)r*F_H+c;
    float y = fmaxf(wc*(x[idx]-am)*inv+bc, 0.f);
    if (mode == 0) {
      l0f[idx] = y;
      unsigned short q = f2b(y);
      loutb[idx] = q;
      jkb[idx] = q;
    } else if (mode == 1) {
      loutb[idx] = f2b(y + l0f[idx]);
      float cur = __uint_as_float(((unsigned)jkb[idx])<<16);
      jkb[idx] = f2b(fmaxf(cur, y));
    } else {
      float cur = __uint_as_float(((unsigned)jkb[idx])<<16);
      jkb[idx] = f2b(fmaxf(cur, y));
    }
  }
}

extern "C" void kernel_launch(void* const* d_in, const int* in_sizes, int n_in,
                              void* d_out, int out_size, void* d_ws, size_t ws_size,
                              hipStream_t stream) {
  (void)in_sizes; (void)n_in; (void)out_size; (void)ws_size;
  const float* x     = (const float*)d_in[0];
  const int*   ei    = (const int*)d_in[1];
  const int*   srcp  = ei;
  const int*   dstp  = ei + N_EDGES;
  const float* Wc[3]  = {(const float*)d_in[2], (const float*)d_in[4], (const float*)d_in[6]};
  const float* bc_[3] = {(const float*)d_in[3], (const float*)d_in[5], (const float*)d_in[7]};
  const float* lin1W = (const float*)d_in[8];
  const float* lin1b = (const float*)d_in[9];
  const float* lin2W = (const float*)d_in[10];
  const float* lin2b = (const float*)d_in[11];
  const float* gw[3] = {(const float*)d_in[12], (const float*)d_in[15], (const float*)d_in[18]};
  const float* gb[3] = {(const float*)d_in[13], (const float*)d_in[16], (const float*)d_in[19]};
  const float* ga[3] = {(const float*)d_in[14], (const float*)d_in[17], (const float*)d_in[20]};

  float* out = (float*)d_out;   // out_size = 92,880,000 floats

  // ---- d_out scratch layout (explicit, non-overlapping in time) ----
  // l0 fp32 [0,10.24M); bf16 buffers: l0b [10.24M,+ACT) hinb jkb t_b; p1 fp32 [57.2M,67.44M)
  float* l0 = out;
  unsigned short* l0b  = (unsigned short*)(out + SZL);
  unsigned short* hinb = (unsigned short*)(out + SZL + ACT);
  unsigned short* jkb  = (unsigned short*)(out + SZL + 2*ACT);
  unsigned short* t_b  = (unsigned short*)(out + SZL + 3*ACT);
  float* p1            = out + 57200000L;

  // ---- ws layout (~74.6 MB) ----
  float* ws   = (float*)d_ws;
  float* p0   = ws;                         // conv0 partial z=0; reused as `agg` afterwards
  float* agg  = ws;
  unsigned short* f1b = (unsigned short*)(ws + SZL);            // lin1 out: ACT floats
  long off = SZL + ACT;
  unsigned short* W0T   = (unsigned short*)(ws + off); off += (long)F_H*KP0/2;
  unsigned short* W1T   = (unsigned short*)(ws + off); off += (long)F_H*F_H/2;
  unsigned short* W2T   = (unsigned short*)(ws + off); off += (long)F_H*F_H/2;
  unsigned short* l1WT  = (unsigned short*)(ws + off); off += (long)F_H*F_H/2;
  unsigned short* l2WT  = (unsigned short*)(ws + off); off += (long)NP2*F_H/2;
  float* dinv = ws + off;                   off += N_NODES;
  float* msum = ws + off;                   off += F_H;
  float* ssum = ws + off;                   off += F_H;
  int* deg    = (int*)(ws + off);           off += N_NODES;
  int* rowptr = (int*)(ws + off);           off += N_NODES + 1;
  int* cursor = (int*)(ws + off);           off += N_NODES;
  int* colsrc = (int*)(ws + off);

  // ---- CSR build ----
  k_zero_i<<<(N_NODES+255)/256,256,0,stream>>>(deg, N_NODES);
  k_degree<<<(N_EDGES+255)/256,256,0,stream>>>(dstp, deg);
  k_dinv<<<(N_NODES+255)/256,256,0,stream>>>(deg, dinv);
  k_scan<<<1,1024,0,stream>>>(deg, rowptr);
  k_copy_i<<<(N_NODES+255)/256,256,0,stream>>>(rowptr, cursor, N_NODES);
  k_scatter<<<(N_EDGES+255)/256,256,0,stream>>>(srcp, dstp, cursor, colsrc);

  // ---- weight conversions (x is consumed fp32 directly by conv0 now) ----
  {
    int n0 = F_H*KP0;   k_cvtT<<<(n0+255)/256,256,0,stream>>>(Wc[0], W0T, F_IN, F_H, F_H, KP0);
    int nh = F_H*F_H;   k_cvtT<<<(nh+255)/256,256,0,stream>>>(Wc[1], W1T, F_H, F_H, F_H, F_H);
                        k_cvtT<<<(nh+255)/256,256,0,stream>>>(Wc[2], W2T, F_H, F_H, F_H, F_H);
                        k_cvtT<<<(nh+255)/256,256,0,stream>>>(lin1W, l1WT, F_H, F_H, F_H, F_H);
    int n2 = NP2*F_H;   k_cvtT<<<(n2+255)/256,256,0,stream>>>(lin2W, l2WT, F_H, F_IN, NP2, F_H);
  }

  // ---- 3 GCN layers ----
  for (int i = 0; i < 3; i++) {
    if (i == 0) {
      // conv0: fp32 A (raw x) with fused cvt; split-K=2: z=0 -> p0 (ws), z=1 -> p1 (d_out)
      long zs = p1 - p0;
      k_gb<1,0,0><<<dim3(F_H/128, N_PAD/128, 2),256,0,stream>>>(x, W0T, nullptr, p0,
          N_NODES, F_H, KP0, F_IN, F_H, KP0/2, zs);
      k_red<<<(int)((SZL/4+255)/256),256,0,stream>>>(p0, p1, t_b);
    } else {
      const unsigned short* Ain = (i==1) ? l0b : hinb;
      const unsigned short* Wt  = (i==1) ? W1T : W2T;
      k_gb<0,1,0><<<dim3(F_H/128, N_PAD/128, 1),256,0,stream>>>(Ain, Wt, nullptr, t_b,
          N_NODES, F_H, F_H, F_H, F_H, F_H, 0L);
    }
    k_agg<<<N_NODES,256,0,stream>>>(t_b, rowptr, colsrc, dinv, bc_[i], agg);
    k_zero_f<<<4,256,0,stream>>>(msum, 1024);   // msum+ssum contiguous
    k_stats<<<N_NODES/STAT_ROWS,512,0,stream>>>(agg, msum, ssum);
    k_final<<<N_NODES/STAT_ROWS,512,0,stream>>>(agg, msum, ssum, gw[i], gb[i], ga[i],
        l0, (i==0)? l0b : hinb, jkb, i);
  }

  // ---- head ----
  k_gb<0,1,1><<<dim3(F_H/128, N_PAD/128, 1),256,0,stream>>>(jkb, l1WT, lin1b, f1b,
      N_NODES, F_H, F_H, F_H, F_H, F_H, 0L);
  k_gb<0,0,0><<<dim3(NP2/128, N_PAD/128, 1),256,0,stream>>>(f1b, l2WT, lin2b, out,
      N_NODES, F_IN, F_H, F_H, F_IN, F_H, 0L);
}

// Round 9
// 1029.072 us; speedup vs baseline: 1.0014x; 1.0014x over previous
//
#include <hip/hip_runtime.h>

#define N_NODES 20000
#define N_PAD   20096      /* 157*128 */
#define N_EDGES 320000
#define F_IN 4644
#define KP0  4672          /* F_IN padded to 32 */
#define NP2  4736          /* F_IN padded to 128 */
#define F_H 512
#define EPSV 1e-5f
#define SZL 10240000L      /* N_NODES*F_H floats */
#define ACT 5200000L       /* floats per bf16 activation buffer: >= N_PAD*F_H/2 = 5,144,576 */

using short8 = __attribute__((ext_vector_type(8))) short;
using f32x4  = __attribute__((ext_vector_type(4))) float;

__device__ inline unsigned short f2b(float f){
  union{float f; unsigned u;} v; v.f=f;
  unsigned u = v.u + 0x7fffu + ((v.u>>16)&1u);
  return (unsigned short)(u>>16);
}
__device__ inline float blo(unsigned v){ return __uint_as_float(v<<16); }
__device__ inline float bhi(unsigned v){ return __uint_as_float(v & 0xffff0000u); }

#define GLDS(g, l) __builtin_amdgcn_global_load_lds( \
    (const __attribute__((address_space(1))) void*)(g), \
    (__attribute__((address_space(3))) void*)(l), 16, 0, 0)

// ---------------- utility / CSR ----------------
// zero deg (20000 ints) + 3 layer stat pairs (3*1024 floats) in one launch
__global__ void k_zero_ds(int* __restrict__ deg, float* __restrict__ st){
  int i = blockIdx.x*blockDim.x+threadIdx.x;
  if (i < N_NODES) deg[i] = 0;
  else if (i < N_NODES + 3072) st[i - N_NODES] = 0.f;
}
__global__ void k_degree(const int* __restrict__ dst, int* __restrict__ deg){
  int e = blockIdx.x*blockDim.x+threadIdx.x;
  if (e < N_EDGES) atomicAdd(&deg[dst[e]], 1);
}
// prefix scan of deg -> rowptr; also emits cursor (=rowptr copy) and dinv
__global__ __launch_bounds__(1024) void k_scan(const int* __restrict__ deg, int* __restrict__ rowptr,
                                               int* __restrict__ cursor, float* __restrict__ dinv){
  __shared__ int sh[1024];
  int t = threadIdx.x;
  const int C = 20;
  int base = t*C;
  int loc[C];
  int s = 0;
  #pragma unroll
  for (int i=0;i<C;i++){ int idx=base+i; int v = (idx<N_NODES)?deg[idx]:0; loc[i]=s; s+=v; }
  sh[t]=s; __syncthreads();
  for (int off=1; off<1024; off<<=1){
    int v = (t>=off)?sh[t-off]:0;
    __syncthreads();
    sh[t]+=v;
    __syncthreads();
  }
  int excl = (t==0)?0:sh[t-1];
  #pragma unroll
  for (int i=0;i<C;i++){
    int idx=base+i;
    if(idx<N_NODES){
      int rv = excl+loc[i];
      rowptr[idx]=rv; cursor[idx]=rv;
      dinv[idx] = rsqrtf((float)(deg[idx]+1));
    }
  }
  if (t==1023) rowptr[N_NODES]=sh[1023];
}
__global__ void k_scatter(const int* __restrict__ src, const int* __restrict__ dst,
                          int* __restrict__ cursor, int* __restrict__ colsrc){
  int e = blockIdx.x*blockDim.x+threadIdx.x;
  if (e < N_EDGES){
    int p = atomicAdd(&cursor[dst[e]], 1);
    colsrc[p] = src[e];
  }
}

// ---------------- conversions ----------------
__global__ void k_cvtT(const float* __restrict__ B, unsigned short* __restrict__ BT,
                       int K, int N, int NP, int KP){
  int t = blockIdx.x*blockDim.x+threadIdx.x;
  if (t >= NP*KP) return;
  int n = t / KP, k = t % KP;
  float v = (n < N && k < K) ? B[(long)k*N + n] : 0.f;
  BT[t] = f2b(v);
}
__global__ void k_cvt_x(const float* __restrict__ x, unsigned short* __restrict__ xb){
  long id = (long)blockIdx.x*256 + threadIdx.x;   // one 8-col chunk
  const int CPR = KP0/8;
  if (id >= (long)N_PAD*CPR) return;
  int row = (int)(id / CPR), c8 = (int)(id % CPR);
  int col = c8*8;
  short8 o;
  if (row < N_NODES && col + 8 <= F_IN) {
    const float* p = &x[(long)row*F_IN + col];
    float4 v0 = *(const float4*)p, v1 = *(const float4*)(p+4);
    o[0]=(short)f2b(v0.x); o[1]=(short)f2b(v0.y); o[2]=(short)f2b(v0.z); o[3]=(short)f2b(v0.w);
    o[4]=(short)f2b(v1.x); o[5]=(short)f2b(v1.y); o[6]=(short)f2b(v1.z); o[7]=(short)f2b(v1.w);
  } else {
    #pragma unroll
    for (int j=0;j<8;j++){
      int cc = col+j;
      float v = (row < N_NODES && cc < F_IN) ? x[(long)row*F_IN + cc] : 0.f;
      o[j] = (short)f2b(v);
    }
  }
  *(short8*)&xb[id*8] = o;
}

// ---------------- bf16 MFMA GEMM: GLDS dbuf + swizzles + full-line epilogue ----------------
// C[M,N] = A[M,K]@BT[N,K]^T. A,BT bf16 row-major; A needs >= gridDim.y*128 readable rows.
// 128x128 tile, BK=32, 4 waves (2x2), 4x4 16x16x32 frags/wave. Single-K (no split).
// XCD-aware bijective block swizzle (T1/m204). LDS k-slot swizzle on 16B slots:
// stored slot = q ^ ((row>>1)&3); swizzle applied on global SOURCE (GLDS dest stays linear)
// and identically on the ds_read address (both-sides rule).
// Epilogue: per-wave LDS transpose -> float4 / 4xushort stores (full cache lines).
template<int OUTB, int RELU>
__global__ __launch_bounds__(256) void k_gb(
    const unsigned short* __restrict__ A, const unsigned short* __restrict__ BT,
    const float* __restrict__ bias, void* __restrict__ Cvoid,
    int M, int N, int KP, int lda, int ldc)
{
  // [0..1] = A double-buffer, [2..3] = B double-buffer; epilogue reuses as fp32 scratch
  __shared__ unsigned short smem[4][4096];
  const int tid  = threadIdx.x;
  // ---- XCD-aware bijective swizzle over flattened (x,y) ----
  const int gx   = gridDim.x;
  const int nwg  = gx * gridDim.y;
  const int orig = blockIdx.x + gx * blockIdx.y;
  const int q = nwg >> 3, r = nwg & 7;
  const int xcd = orig & 7, sub = orig >> 3;
  const int wg  = (xcd < r ? xcd*(q+1) : r*(q+1) + (xcd - r)*q) + sub;
  const int bn  = (wg % gx) * 128;
  const int bm  = (wg / gx) * 128;
  const int wave = tid >> 6, lane = tid & 63;
  const int wm = (wave & 1) * 64, wn = (wave >> 1) * 64;
  const int l15 = lane & 15, l4 = lane >> 4;

  f32x4 acc[4][4];
  #pragma unroll
  for (int m=0;m<4;m++)
    #pragma unroll
    for (int n=0;n<4;n++) acc[m][n] = (f32x4){0.f,0.f,0.f,0.f};

  // 16B chunks: tile = 512 chunks = 128 rows x 4 slots; chunk c -> row c>>2, slot c&3.
  const int c0 = wave*64 + lane;
  const int c1 = c0 + 256;
  const long ar0 = bm + (c0 >> 2); const int as0 = ((c0 & 3) ^ ((c0 >> 3) & 3))*8;
  const long ar1 = bm + (c1 >> 2); const int as1 = ((c1 & 3) ^ ((c1 >> 3) & 3))*8;
  const long br0 = bn + (c0 >> 2);
  const long br1 = bn + (c1 >> 2);
  const int ldA0 = wave*512;          // ushort offset of this wave's chunk group (issue 0)
  const int ldA1 = 2048 + wave*512;   // issue 1

  // read-side swizzle: k-slot l4 of row (…+l15) lives at slot l4 ^ ((l15>>1)&3)
  const int kro = (l4 ^ ((l15 >> 1) & 3)) * 8;

  const int nit = KP >> 5;

  // prologue: stage tile 0 into buffer 0
  GLDS(A + ar0*lda + as0, &smem[0][ldA0]);
  GLDS(A + ar1*lda + as1, &smem[0][ldA1]);
  GLDS(BT + br0*KP + as0, &smem[2][ldA0]);
  GLDS(BT + br1*KP + as1, &smem[2][ldA1]);
  __syncthreads();

  int cur = 0;
  for (int it = 0; it < nit; ++it) {
    if (it + 1 < nit) {
      const int kn = (it+1)*32;
      GLDS(A + ar0*lda + (kn + as0), &smem[cur^1][ldA0]);
      GLDS(A + ar1*lda + (kn + as1), &smem[cur^1][ldA1]);
      GLDS(BT + br0*KP + (kn + as0), &smem[2+(cur^1)][ldA0]);
      GLDS(BT + br1*KP + (kn + as1), &smem[2+(cur^1)][ldA1]);
    }

    short8 af[4], bf[4];
    #pragma unroll
    for (int m=0;m<4;m++) af[m] = *(const short8*)&smem[cur][(wm + m*16 + l15)*32 + kro];
    #pragma unroll
    for (int n=0;n<4;n++) bf[n] = *(const short8*)&smem[2+cur][(wn + n*16 + l15)*32 + kro];
    #pragma unroll
    for (int m=0;m<4;m++)
      #pragma unroll
      for (int n=0;n<4;n++)
        acc[m][n] = __builtin_amdgcn_mfma_f32_16x16x32_bf16(af[m], bf[n], acc[m][n], 0, 0, 0);

    __syncthreads();   // drains prefetch + all waves' ds_reads
    cur ^= 1;
  }

  // ---- full-line epilogue via per-wave LDS transpose ----
  // per wave: 16 rows x 64 cols fp32, row stride 68 (16B-aligned, conflict-light)
  float* eb = ((float*)smem) + wave*1088;   // 4*1088*4B = 17408B <= 32KB
  float* Cf = (float*)Cvoid;
  unsigned short* Cb = (unsigned short*)Cvoid;
  #pragma unroll
  for (int m=0;m<4;m++){
    #pragma unroll
    for (int n=0;n<4;n++)
      #pragma unroll
      for (int r2=0;r2<4;r2++)
        eb[(l4*4+r2)*68 + n*16 + l15] = acc[m][n][r2];
    __syncthreads();
    const int row0 = bm + wm + m*16;
    #pragma unroll
    for (int i=0;i<4;i++){
      int idx = i*64 + lane;          // 0..255 float4-chunks of the 16x64 tile
      int rr  = idx >> 4;             // 0..15
      int c4  = (idx & 15) * 4;       // 0,4,..,60
      int row = row0 + rr;
      int col = bn + wn + c4;
      if (row < M) {
        float4 v = *(float4*)&eb[rr*68 + c4];
        float vv[4] = {v.x, v.y, v.z, v.w};
        if (col + 3 < N) {
          #pragma unroll
          for (int j=0;j<4;j++){
            float zz = vv[j] + (bias ? bias[col+j] : 0.f);
            vv[j] = RELU ? fmaxf(zz, 0.f) : zz;
          }
          if (OUTB) {
            unsigned short o[4] = { f2b(vv[0]), f2b(vv[1]), f2b(vv[2]), f2b(vv[3]) };
            *(uint2*)&Cb[(long)row*ldc + col] = *(uint2*)o;
          } else {
            float4 ov = {vv[0], vv[1], vv[2], vv[3]};
            *(float4*)&Cf[(long)row*ldc + col] = ov;
          }
        } else {
          #pragma unroll
          for (int j=0;j<4;j++){
            int cc = col + j;
            if (cc < N) {
              float zz = vv[j] + (bias ? bias[cc] : 0.f);
              if (RELU) zz = fmaxf(zz, 0.f);
              if (OUTB) Cb[(long)row*ldc + cc] = f2b(zz);
              else      Cf[(long)row*ldc + cc] = zz;
            }
          }
        }
      }
    }
    __syncthreads();
  }
}

// ---------------- GCN aggregation (bf16 h, fp32 accumulate) ----------------
__global__ __launch_bounds__(256) void k_agg(const unsigned short* __restrict__ h,
    const int* __restrict__ rowptr, const int* __restrict__ colsrc,
    const float* __restrict__ dinv, const float* __restrict__ bias,
    float* __restrict__ out)
{
  int d = blockIdx.x;
  int t = threadIdx.x;                 // channel pair 2t,2t+1
  const unsigned* h32 = (const unsigned*)h;
  float di = dinv[d];
  int beg = rowptr[d], end = rowptr[d+1];
  float a0 = 0.f, a1 = 0.f;
  for (int e = beg; e < end; e++) {
    int s = colsrc[e];
    float cf = dinv[s]*di;
    unsigned v = h32[(long)s*256 + t];
    a0 += blo(v)*cf;
    a1 += bhi(v)*cf;
  }
  unsigned v = h32[(long)d*256 + t];
  float sc = di*di;
  a0 += blo(v)*sc;
  a1 += bhi(v)*sc;
  float2 o; o.x = a0 + bias[2*t]; o.y = a1 + bias[2*t+1];
  *(float2*)&out[(long)d*F_H + 2*t] = o;
}

// ---------------- GraphNorm: fused sum+sumsq, then normalize ----------------
#define STAT_ROWS 50
__global__ __launch_bounds__(512) void k_stats(const float* __restrict__ x,
    float* __restrict__ msum, float* __restrict__ ssum){
  int c = threadIdx.x;
  int r0 = blockIdx.x*STAT_ROWS;
  float s = 0.f, s2 = 0.f;
  for (int r=r0;r<r0+STAT_ROWS;r++){ float v = x[(long)r*F_H+c]; s += v; s2 += v*v; }
  atomicAdd(&msum[c], s);
  atomicAdd(&ssum[c], s2);
}
// mode 0: l0f=y, l0b=bf16(y), jkb=bf16(y); mode 1: loutb=bf16(y+l0f), jkb=max; mode 2: jkb=max
__global__ __launch_bounds__(512) void k_final(const float* __restrict__ x,
    const float* __restrict__ msum, const float* __restrict__ ssum,
    const float* __restrict__ w, const float* __restrict__ b, const float* __restrict__ a,
    float* __restrict__ l0f, unsigned short* __restrict__ loutb,
    unsigned short* __restrict__ jkb, int mode)
{
  int c = threadIdx.x;
  float mean = msum[c]*(1.f/N_NODES);
  float aa = a[c];
  float var = ssum[c]*(1.f/N_NODES) - mean*mean*aa*(2.f-aa);
  float inv = rsqrtf(var + EPSV);
  float am = aa*mean;
  float wc = w[c], bc = b[c];
  int r0 = blockIdx.x*STAT_ROWS;
  for (int r=r0;r<r0+STAT_ROWS;r++){
    long idx = (long)r*F_H+c;
    float y = fmaxf(wc*(x[idx]-am)*inv+bc, 0.f);
    if (mode == 0) {
      l0f[idx] = y;
      unsigned short q = f2b(y);
      loutb[idx] = q;
      jkb[idx] = q;
    } else if (mode == 1) {
      loutb[idx] = f2b(y + l0f[idx]);
      float cur = __uint_as_float(((unsigned)jkb[idx])<<16);
      jkb[idx] = f2b(fmaxf(cur, y));
    } else {
      float cur = __uint_as_float(((unsigned)jkb[idx])<<16);
      jkb[idx] = f2b(fmaxf(cur, y));
    }
  }
}

extern "C" void kernel_launch(void* const* d_in, const int* in_sizes, int n_in,
                              void* d_out, int out_size, void* d_ws, size_t ws_size,
                              hipStream_t stream) {
  (void)in_sizes; (void)n_in; (void)out_size; (void)ws_size;
  const float* x     = (const float*)d_in[0];
  const int*   ei    = (const int*)d_in[1];
  const int*   srcp  = ei;
  const int*   dstp  = ei + N_EDGES;
  const float* Wc[3]  = {(const float*)d_in[2], (const float*)d_in[4], (const float*)d_in[6]};
  const float* bc_[3] = {(const float*)d_in[3], (const float*)d_in[5], (const float*)d_in[7]};
  const float* lin1W = (const float*)d_in[8];
  const float* lin1b = (const float*)d_in[9];
  const float* lin2W = (const float*)d_in[10];
  const float* lin2b = (const float*)d_in[11];
  const float* gw[3] = {(const float*)d_in[12], (const float*)d_in[15], (const float*)d_in[18]};
  const float* gb[3] = {(const float*)d_in[13], (const float*)d_in[16], (const float*)d_in[19]};
  const float* ga[3] = {(const float*)d_in[14], (const float*)d_in[17], (const float*)d_in[20]};

  float* out = (float*)d_out;   // out_size = 92,880,000 floats

  // ---- d_out scratch layout ----
  // l0 fp32 [0, 10.24M)
  // xb bf16 [10.24M, 57.19M)  live cvt_x -> conv0; recycled after conv0 as:
  //   l0b [10.24M,+ACT)  hinb [+ACT,+2ACT)  jkb [+2ACT,+3ACT)
  // t_b bf16 [57.20M, 62.36M)  (outside xb: conv0 writes it while xb is live)
  float* l0 = out;
  unsigned short* xb   = (unsigned short*)(out + SZL);
  unsigned short* l0b  = (unsigned short*)(out + SZL);
  unsigned short* hinb = (unsigned short*)(out + SZL + ACT);
  unsigned short* jkb  = (unsigned short*)(out + SZL + 2*ACT);
  unsigned short* t_b  = (unsigned short*)(out + 57200000L);

  // ---- ws layout (~74.6 MB; proven >= 93 MB available in R2) ----
  float* ws   = (float*)d_ws;
  float* agg  = ws;                                             // SZL
  unsigned short* f1b = (unsigned short*)(ws + SZL);            // ACT floats
  long off = SZL + ACT;
  unsigned short* W0T   = (unsigned short*)(ws + off); off += (long)F_H*KP0/2;
  unsigned short* W1T   = (unsigned short*)(ws + off); off += (long)F_H*F_H/2;
  unsigned short* W2T   = (unsigned short*)(ws + off); off += (long)F_H*F_H/2;
  unsigned short* l1WT  = (unsigned short*)(ws + off); off += (long)F_H*F_H/2;
  unsigned short* l2WT  = (unsigned short*)(ws + off); off += (long)NP2*F_H/2;
  float* dinv  = ws + off;                  off += N_NODES;
  float* stats = ws + off;                  off += 3*1024;      // 3 layers x (msum|ssum)
  int* deg    = (int*)(ws + off);           off += N_NODES;
  int* rowptr = (int*)(ws + off);           off += N_NODES + 1;
  int* cursor = (int*)(ws + off);           off += N_NODES;
  int* colsrc = (int*)(ws + off);

  // ---- CSR build (4 launches) ----
  k_zero_ds<<<(N_NODES+3072+255)/256,256,0,stream>>>(deg, stats);
  k_degree<<<(N_EDGES+255)/256,256,0,stream>>>(dstp, deg);
  k_scan<<<1,1024,0,stream>>>(deg, rowptr, cursor, dinv);
  k_scatter<<<(N_EDGES+255)/256,256,0,stream>>>(srcp, dstp, cursor, colsrc);

  // ---- conversions ----
  {
    int n0 = F_H*KP0;   k_cvtT<<<(n0+255)/256,256,0,stream>>>(Wc[0], W0T, F_IN, F_H, F_H, KP0);
    int nh = F_H*F_H;   k_cvtT<<<(nh+255)/256,256,0,stream>>>(Wc[1], W1T, F_H, F_H, F_H, F_H);
                        k_cvtT<<<(nh+255)/256,256,0,stream>>>(Wc[2], W2T, F_H, F_H, F_H, F_H);
                        k_cvtT<<<(nh+255)/256,256,0,stream>>>(lin1W, l1WT, F_H, F_H, F_H, F_H);
    int n2 = NP2*F_H;   k_cvtT<<<(n2+255)/256,256,0,stream>>>(lin2W, l2WT, F_H, F_IN, NP2, F_H);
    long nx = (long)N_PAD*(KP0/8);
    k_cvt_x<<<(int)((nx+255)/256),256,0,stream>>>(x, xb);
  }

  // ---- 3 GCN layers ----
  for (int i = 0; i < 3; i++) {
    float* msum = stats + i*1024;
    float* ssum = msum + 512;
    if (i == 0) {
      // single-K conv0: 628 blocks, all co-resident (no scheduling rounds), bf16 out
      k_gb<1,0><<<dim3(F_H/128, N_PAD/128),256,0,stream>>>(xb, W0T, nullptr, t_b,
          N_NODES, F_H, KP0, KP0, F_H);
    } else {
      const unsigned short* Ain = (i==1) ? l0b : hinb;
      const unsigned short* Wt  = (i==1) ? W1T : W2T;
      k_gb<1,0><<<dim3(F_H/128, N_PAD/128),256,0,stream>>>(Ain, Wt, nullptr, t_b,
          N_NODES, F_H, F_H, F_H, F_H);
    }
    k_agg<<<N_NODES,256,0,stream>>>(t_b, rowptr, colsrc, dinv, bc_[i], agg);
    k_stats<<<N_NODES/STAT_ROWS,512,0,stream>>>(agg, msum, ssum);
    k_final<<<N_NODES/STAT_ROWS,512,0,stream>>>(agg, msum, ssum, gw[i], gb[i], ga[i],
        l0, (i==0)? l0b : hinb, jkb, i);
  }

  // ---- head ----
  k_gb<1,1><<<dim3(F_H/128, N_PAD/128),256,0,stream>>>(jkb, l1WT, lin1b, f1b,
      N_NODES, F_H, F_H, F_H, F_H);
  k_gb<0,0><<<dim3(NP2/128, N_PAD/128),256,0,stream>>>(f1b, l2WT, lin2b, out,
      N_NODES, F_IN, F_H, F_H, F_IN);
}